// Round 14
// baseline (138.722 us; speedup 1.0000x reference)
//
#include <hip/hip_runtime.h>
#include <float.h>

#define CC 256
#define HH 200
#define WW 320
#define HW (HH * WW)
#define MM 14
#define CG 4             // channel-group blocks per (roi, bin-row)
#define CPB (CC / CG)    // 64 channels per block
#define KPW 16           // channels per wave (4 waves x 16 = 64)

__global__ void roi_init(float* __restrict__ binmax) {
    int t = blockIdx.x * blockDim.x + threadIdx.x;
    if (t < MM * MM) binmax[t] = -FLT_MAX;
}

__device__ inline void atomicMaxF(float* addr, float val) {
    // Ordered-int trick: valid for finite floats.
    if (val >= 0.0f) {
        atomicMax((int*)addr, __float_as_int(val));
    } else {
        atomicMin((unsigned int*)addr, __float_as_uint(val));
    }
}

// v11: address-halving test. v9 (gather) and v10 (staged) converge at 50 us
// with no pipe saturated -> hypothesis: per-CU TA address throughput
// (~2 addr/cy) is the shared resource (v9: 229K addr/CU ~ 118K cy). This
// version halves addresses on the 56% of ROIs where sw <= 6 (BLOCK-uniform):
// one float4 per bilinear row covers BOTH j-sample corner pairs
// (d = x1c_j1 - x1c_j0 <= 2). Lane = (channel-half, i, n): 28 lanes/channel,
// 2 channels per wave-slot, 2 dwordx4 loads per lane-slot. j1 extracted via
// a per-lane CONSTANT 4-wide weight vector (no runtime vector indexing).
// Rows stay lane-contiguous (v8 lesson). Slow path = v9 with the 8
// duplicate lanes masked. If time does NOT follow the address count, the
// ~50us is an L1-line-delivery floor shared by all designs -> roofline.
__global__ __launch_bounds__(256, 8) void roi_reduce(
    const float* __restrict__ feature,
    const float* __restrict__ rois,
    float* __restrict__ binmax)
{
    const int bid = blockIdx.x;
    const int cg  = bid & (CG - 1);
    const int rm  = bid >> 2;          // CG == 4
    const int m   = rm % MM;
    const int r   = rm / MM;
    const int tid = threadIdx.x;
    const int w    = tid >> 6;         // wave id 0..3 = channel quarter
    const int lane = tid & 63;
    const int cbase = cg * CPB + w * KPW;

    const float ry1 = rois[r * 4 + 0];
    const float rx1 = rois[r * 4 + 1];
    const float ry2 = rois[r * 4 + 2];
    const float rx2 = rois[r * 4 + 3];
    const float sh = (ry2 - ry1) * (1.0f / 14.0f);
    const float sw = (rx2 - rx1) * (1.0f / 14.0f);
    const float f13 = 1.0f / 3.0f, f23 = 2.0f / 3.0f;

    const bool fastp = (sw <= 6.0f);   // block-uniform: guarantees d <= 2

    typedef float f4v __attribute__((ext_vector_type(4)));
    typedef f4v __attribute__((aligned(4))) f4u;   // 4B-aligned float4 load
    typedef float f2v __attribute__((ext_vector_type(2)));
    typedef f2v __attribute__((aligned(4))) f2u;   // 4B-aligned float2 load

    float lmax = -FLT_MAX;

    if (fastp) {
        if (lane < 56) {
            // lane = half*28 + ii*14 + nn (nn fastest: x-monotone runs;
            // row changes only every 14 lanes -- v8's winning layout).
            const int half = lane / 28;        // channel parity in the pair
            const int u    = lane % 28;
            const int ii   = u / 14;           // sample row (yA/yB)
            const int nn   = u % 14;           // bin column

            // y side (reference clamp semantics).
            const float y = ry1 + sh * (float)m + sh * (ii ? f23 : f13);
            const int y1c = min(max((int)floorf(y), 0), HH - 1);
            const int y2c = min(max((int)floorf(y) + 1, 0), HH - 1);
            const float wylo = y - (float)y1c, wyhi = (float)y2c - y;

            // x side: both j samples of bin nn.
            const float x0 = rx1 + sw * (float)nn + sw * f13;
            const float x1 = rx1 + sw * (float)nn + sw * f23;
            const int x1c0 = min(max((int)floorf(x0), 0), WW - 1);
            const int x2c0 = min(max((int)floorf(x0) + 1, 0), WW - 1);
            const int x1c1 = min(max((int)floorf(x1), 0), WW - 1);
            const int x2c1 = min(max((int)floorf(x1) + 1, 0), WW - 1);
            const float wxlo0 = x0 - (float)x1c0, wxhi0 = (float)x2c0 - x0;
            const float wxlo1 = x1 - (float)x1c1, wxhi1 = (float)x2c1 - x1;

            // float4 base: x1c0 <= ~302 < WW-4 always -> base == x1c0, o0 == 0.
            const int base = min(x1c0, WW - 4);      // defensive
            int o1 = x1c1 - base;
            o1 = min(max(o1, 0), 2);                 // defensive (sw<=6 -> <=2)

            // Per-lane constant weight vector for j1 (positions o1, o1+1).
            f4v wj1;
            wj1.x = (o1 == 0) ? wxhi1 : 0.0f;
            wj1.y = (o1 == 0) ? wxlo1 : ((o1 == 1) ? wxhi1 : 0.0f);
            wj1.z = (o1 == 1) ? wxlo1 : ((o1 == 2) ? wxhi1 : 0.0f);
            wj1.w = (o1 == 2) ? wxlo1 : 0.0f;

            // Row pointers; channel = cbase + 2*it + half.
            const float* p1 = feature + ((size_t)(cbase + half)) * HW + y1c * WW + base;
            const float* p2 = feature + ((size_t)(cbase + half)) * HW + y2c * WW + base;

            #pragma unroll 4
            for (int it = 0; it < 8; ++it) {
                f4v a4 = *(const f4u*)p1;
                f4v b4 = *(const f4u*)p2;
                p1 += 2 * HW;
                p2 += 2 * HW;
                // j0: corners at positions 0,1.
                float pa0 = a4.x * wxhi0 + a4.y * wxlo0;
                float pb0 = b4.x * wxhi0 + b4.y * wxlo0;
                float s0  = pa0 * wyhi + pb0 * wylo;
                // j1: dot with the sparse weight vector.
                float pa1 = a4.x * wj1.x + a4.y * wj1.y + a4.z * wj1.z + a4.w * wj1.w;
                float pb1 = b4.x * wj1.x + b4.y * wj1.y + b4.z * wj1.z + b4.w * wj1.w;
                float s1  = pa1 * wyhi + pb1 * wylo;
                lmax = fmaxf(lmax, fmaxf(s0, s1));
            }
        }
    } else {
        // Slow path: v9 exactly, with lanes 56..63 masked (not duplicated).
        if (lane < 56) {
            const int s   = lane;              // s = ii*28 + nn*2 + jj
            const int ii  = s / 28;
            const int rem = s % 28;
            const int nn  = rem >> 1;
            const int jj  = rem & 1;

            const float y = ry1 + sh * (float)m + sh * (ii ? f23 : f13);
            const float x = rx1 + sw * (float)nn + sw * (jj ? f23 : f13);

            const int y1c = min(max((int)floorf(y), 0), HH - 1);
            const int y2c = min(max((int)floorf(y) + 1, 0), HH - 1);
            const int x1c = min(max((int)floorf(x), 0), WW - 1);
            const int x2c = min(max((int)floorf(x) + 1, 0), WW - 1);
            const float wylo = y - (float)y1c, wyhi = (float)y2c - y;
            const float wxlo = x - (float)x1c, wxhi = (float)x2c - x;
            const bool csel = (x2c == x1c);    // unreachable; safety only

            const float* pA = feature + (size_t)cbase * HW + y1c * WW + x1c;
            const float* pB = feature + (size_t)cbase * HW + y2c * WW + x1c;

            #pragma unroll 4
            for (int kk = 0; kk < KPW; ++kk) {
                f2v a = *(const f2u*)pA;
                f2v b = *(const f2u*)pB;
                pA += HW;
                pB += HW;
                float ax2 = csel ? a.x : a.y;
                float bx2 = csel ? b.x : b.y;
                float p = a.x * wxhi + ax2 * wxlo;
                float q = b.x * wxhi + bx2 * wxlo;
                lmax = fmaxf(lmax, p * wyhi + q * wylo);
            }
        }
    }

    __shared__ float pmax[224];
    if (lane < 56) pmax[w * 56 + lane] = lmax;
    __syncthreads();
    if (tid < MM) {  // one thread per bin n
        float v = -FLT_MAX;
        if (fastp) {
            // fast lanes: half*28 + ii*14 + nn -> offsets {0,14,28,42} + n
            #pragma unroll
            for (int c4 = 0; c4 < 4; ++c4) {
                const float* pw = &pmax[c4 * 56 + tid];
                v = fmaxf(v, fmaxf(fmaxf(pw[0], pw[14]), fmaxf(pw[28], pw[42])));
            }
        } else {
            // slow lanes: ii*28 + n*2 + jj -> offsets {0,1,28,29} + 2n
            #pragma unroll
            for (int c4 = 0; c4 < 4; ++c4) {
                const float* pw = &pmax[c4 * 56 + tid * 2];
                v = fmaxf(v, fmaxf(fmaxf(pw[0], pw[1]), fmaxf(pw[28], pw[29])));
            }
        }
        atomicMaxF(&binmax[m * MM + tid], v);
    }
}

__global__ __launch_bounds__(256) void roi_bcast(
    const float* __restrict__ binmax, float4* __restrict__ out, int total4)
{
    __shared__ float4 b4[49];  // 196 floats = 49 float4, aligned with bin period
    int t = threadIdx.x;
    if (t < 49) b4[t] = ((const float4*)binmax)[t];
    __syncthreads();
    const int stride = gridDim.x * 256;
    for (int idx = blockIdx.x * 256 + t; idx < total4; idx += stride)
        out[idx] = b4[idx % 49];
}

extern "C" void kernel_launch(void* const* d_in, const int* in_sizes, int n_in,
                              void* d_out, int out_size, void* d_ws, size_t ws_size,
                              hipStream_t stream) {
    const float* feature = (const float*)d_in[0];
    const float* rois    = (const float*)d_in[1];
    float* binmax = (float*)d_ws;
    float* out    = (float*)d_out;

    const int R = in_sizes[1] / 4;

    roi_init<<<1, 256, 0, stream>>>(binmax);
    roi_reduce<<<R * MM * CG, 256, 0, stream>>>(feature, rois, binmax);

    const int total4 = out_size / 4;
    int nb = (total4 + 255) / 256;
    if (nb > 2048) nb = 2048;
    roi_bcast<<<nb, 256, 0, stream>>>(binmax, (float4*)out, total4);
}